// Round 14
// baseline (324.916 us; speedup 1.0000x reference)
//
#include <hip/hip_runtime.h>
#include <hip/hip_bf16.h>
#include <stdint.h>

typedef __attribute__((ext_vector_type(4))) float f32x4;
typedef __attribute__((ext_vector_type(8))) short bf16x8;

#define SEQ 2048
#define HIDDEN 2880
#define NQ 64
#define NKV 8
#define HD 64
#define QKV_DIM 5120
#define Q_SZ 4096
#define K_SZ 512
#define OW_N 2880
#define OW_NPAD 2944
#define OW_K 4096

__device__ __forceinline__ unsigned short f2b_bits(float f) {
    unsigned int x = __float_as_uint(f);
    unsigned int r = (x + 0x7fffu + ((x >> 16) & 1u)) >> 16;  // RNE
    return (unsigned short)r;
}
__device__ __forceinline__ float b2f(unsigned short u) {
    return __uint_as_float(((unsigned int)u) << 16);
}

__device__ __forceinline__ void llds16(const ushort* g, ushort* l) {
    __builtin_amdgcn_global_load_lds(
        (const __attribute__((address_space(1))) void*)g,
        (__attribute__((address_space(3))) void*)l, 16, 0, 0);
}

// ---------------- fused fp32 -> bf16 conversion (hidden + qkv_w + o_w padded) ----------------
__global__ void convert_all(const float* __restrict__ hidden, const float* __restrict__ qkv_w,
                            const float* __restrict__ o_w, ushort* __restrict__ hs_bf,
                            ushort* __restrict__ wqkv_bf, ushort* __restrict__ wo_bf) {
    const int N1 = SEQ * HIDDEN / 4;                 // 1,474,560
    const int N2 = N1 + QKV_DIM * HIDDEN / 4;        // 5,160,960
    const int N3 = N2 + OW_NPAD * OW_K / 4;          // 8,175,616
    int i = blockIdx.x * blockDim.x + threadIdx.x;
    int stride = gridDim.x * blockDim.x;
    for (; i < N3; i += stride) {
        const float* src;
        ushort* dst;
        int j;
        if (i < N1) {
            j = i; src = hidden; dst = hs_bf;
        } else if (i < N2) {
            j = i - N1; src = qkv_w; dst = wqkv_bf;
        } else {
            j = i - N2; src = o_w; dst = wo_bf;
            if ((j >> 10) >= OW_N) {  // padded rows (row = j*4/4096)
                reinterpret_cast<ushort4*>(dst)[j] = make_ushort4(0, 0, 0, 0);
                continue;
            }
        }
        float4 v = reinterpret_cast<const float4*>(src)[j];
        reinterpret_cast<ushort4*>(dst)[j] =
            make_ushort4(f2b_bits(v.x), f2b_bits(v.y), f2b_bits(v.z), f2b_bits(v.w));
    }
}

// ---------------- bf16 GEMM, B^T layout, 128x128 tile, BK=64, single-buffered (r6/r9 proven) ----------------
template<int OUT_BF16>
__global__ __launch_bounds__(256) void gemm_bt(
    const ushort* __restrict__ A, const ushort* __restrict__ B,
    const float* __restrict__ bias, void* __restrict__ Cout,
    int M, int N, int K, int Nreal, int ldC)
{
    __shared__ __align__(16) ushort As[128 * 64];
    __shared__ __align__(16) ushort Bs[128 * 64];
    const int tid = threadIdx.x;
    const int lane = tid & 63;
    const int w = tid >> 6;
    const int wr = w >> 1, wc = w & 1;

    const int nwg = gridDim.x;
    const int per = nwg >> 3;
    const int wgid = (blockIdx.x & 7) * per + (blockIdx.x >> 3);
    const int m0 = (wgid & 15) * 128;   // M-tile fastest (16 M-tiles)
    const int n0 = (wgid >> 4) * 128;   // N-tile chunk-contiguous per XCD

    f32x4 acc[4][4] = {};

    for (int k0 = 0; k0 < K; k0 += 64) {
        #pragma unroll
        for (int it = 0; it < 4; ++it) {
            int i = it * 256 + tid;
            int row = i >> 3;
            int col16 = (i ^ (row & 7)) & 7;
            llds16(A + (size_t)(m0 + row) * K + k0 + col16 * 8,
                   As + (size_t)(it * 256 + (tid & ~63)) * 8);
            llds16(B + (size_t)(n0 + row) * K + k0 + col16 * 8,
                   Bs + (size_t)(it * 256 + (tid & ~63)) * 8);
        }
        __syncthreads();
        #pragma unroll
        for (int kk = 0; kk < 2; ++kk) {
            bf16x8 a[4], b[4];
            #pragma unroll
            for (int mi = 0; mi < 4; ++mi) {
                int row = wr * 64 + mi * 16 + (lane & 15);
                int byte = row * 128 + kk * 64 + (lane >> 4) * 16;
                byte ^= (row & 7) << 4;
                a[mi] = *reinterpret_cast<const bf16x8*>(reinterpret_cast<const char*>(As) + byte);
            }
            #pragma unroll
            for (int ni = 0; ni < 4; ++ni) {
                int row = wc * 64 + ni * 16 + (lane & 15);
                int byte = row * 128 + kk * 64 + (lane >> 4) * 16;
                byte ^= (row & 7) << 4;
                b[ni] = *reinterpret_cast<const bf16x8*>(reinterpret_cast<const char*>(Bs) + byte);
            }
            #pragma unroll
            for (int mi = 0; mi < 4; ++mi)
                #pragma unroll
                for (int ni = 0; ni < 4; ++ni)
                    acc[mi][ni] = __builtin_amdgcn_mfma_f32_16x16x32_bf16(a[mi], b[ni], acc[mi][ni], 0, 0, 0);
        }
        __syncthreads();
    }

    #pragma unroll
    for (int mi = 0; mi < 4; ++mi) {
        int gr = m0 + wr * 64 + mi * 16 + (lane >> 4) * 4;
        #pragma unroll
        for (int ni = 0; ni < 4; ++ni) {
            int gc = n0 + wc * 64 + ni * 16 + (lane & 15);
            if (gc < Nreal) {
                float bv = bias[gc];
                #pragma unroll
                for (int r = 0; r < 4; ++r) {
                    float v = acc[mi][ni][r] + bv;
                    if (OUT_BF16)
                        ((ushort*)Cout)[(size_t)(gr + r) * ldC + gc] = f2b_bits(v);
                    else
                        ((float*)Cout)[(size_t)(gr + r) * ldC + gc] = v;
                }
            }
        }
    }
}

// ---------------- bf16 GEMM, 64x128 tile (O-proj; r9 proven) ----------------
template<int OUT_BF16>
__global__ __launch_bounds__(256) void gemm_bt64(
    const ushort* __restrict__ A, const ushort* __restrict__ B,
    const float* __restrict__ bias, void* __restrict__ Cout,
    int M, int N, int K, int Nreal, int ldC)
{
    __shared__ __align__(16) ushort As[64 * 64];
    __shared__ __align__(16) ushort Bs[128 * 64];
    const int tid = threadIdx.x;
    const int lane = tid & 63;
    const int w = tid >> 6;
    const int l15 = lane & 15;
    const int l4 = lane >> 4;

    const int nwg = gridDim.x;
    const int per = nwg >> 3;
    const int wgid = (blockIdx.x & 7) * per + (blockIdx.x >> 3);
    const int m0 = (wgid & 31) * 64;    // M-tile fastest (32 M-tiles)
    const int n0 = (wgid >> 5) * 128;   // N-tile chunk-contiguous per XCD

    f32x4 acc[4][2] = {};

    for (int k0 = 0; k0 < K; k0 += 64) {
        #pragma unroll
        for (int it = 0; it < 2; ++it) {
            int i = it * 256 + tid;
            int row = i >> 3;
            int col16 = (i ^ (row & 7)) & 7;
            llds16(A + (size_t)(m0 + row) * K + k0 + col16 * 8,
                   As + (size_t)(it * 256 + (tid & ~63)) * 8);
        }
        #pragma unroll
        for (int it = 0; it < 4; ++it) {
            int i = it * 256 + tid;
            int row = i >> 3;
            int col16 = (i ^ (row & 7)) & 7;
            llds16(B + (size_t)(n0 + row) * K + k0 + col16 * 8,
                   Bs + (size_t)(it * 256 + (tid & ~63)) * 8);
        }
        __syncthreads();
        #pragma unroll
        for (int kk = 0; kk < 2; ++kk) {
            bf16x8 a[4], b[2];
            #pragma unroll
            for (int mi = 0; mi < 4; ++mi) {
                int row = mi * 16 + l15;
                int byte = row * 128 + kk * 64 + l4 * 16;
                byte ^= (row & 7) << 4;
                a[mi] = *reinterpret_cast<const bf16x8*>(reinterpret_cast<const char*>(As) + byte);
            }
            #pragma unroll
            for (int ni = 0; ni < 2; ++ni) {
                int row = w * 32 + ni * 16 + l15;
                int byte = row * 128 + kk * 64 + l4 * 16;
                byte ^= (row & 7) << 4;
                b[ni] = *reinterpret_cast<const bf16x8*>(reinterpret_cast<const char*>(Bs) + byte);
            }
            #pragma unroll
            for (int mi = 0; mi < 4; ++mi)
                #pragma unroll
                for (int ni = 0; ni < 2; ++ni)
                    acc[mi][ni] = __builtin_amdgcn_mfma_f32_16x16x32_bf16(a[mi], b[ni], acc[mi][ni], 0, 0, 0);
        }
        __syncthreads();
    }

    #pragma unroll
    for (int mi = 0; mi < 4; ++mi) {
        int gr = m0 + mi * 16 + l4 * 4;
        #pragma unroll
        for (int ni = 0; ni < 2; ++ni) {
            int gc = n0 + w * 32 + ni * 16 + l15;
            if (gc < Nreal) {
                float bv = bias[gc];
                #pragma unroll
                for (int r = 0; r < 4; ++r) {
                    float v = acc[mi][ni][r] + bv;
                    if (OUT_BF16)
                        ((ushort*)Cout)[(size_t)(gr + r) * ldC + gc] = f2b_bits(v);
                    else
                        ((float*)Cout)[(size_t)(gr + r) * ldC + gc] = v;
                }
            }
        }
    }
}

// ---------------- RoPE (YaRN) + split + q-prescale ----------------
__global__ __launch_bounds__(256) void rope_kernel(
    const ushort* __restrict__ qkv, const int* __restrict__ pos,
    ushort* __restrict__ q_ro, ushort* __restrict__ k_ro)
{
    __shared__ float cosv[32], sinv[32];
    const int s = blockIdx.x;
    const int tid = threadIdx.x;
    if (tid < 32) {
        int j = tid;
        const float logbase = logf(150000.0f);
        float freq = expf((float)j * (logbase / 32.0f));  // BASE^(j/32)
        float interp = 1.0f / (32.0f * freq);
        float extrap = 1.0f / freq;
        const float twopi = 6.283185307179586f;
        float low  = 32.0f * logf(4096.0f / (32.0f * twopi)) / logbase;
        float high = 32.0f * logf(4096.0f / (1.0f  * twopi)) / logbase;
        float ramp = ((float)j - low) / (high - low);
        float mask = 1.0f - fminf(fmaxf(ramp, 0.0f), 1.0f);
        float inv_freq = interp * (1.0f - mask) + extrap * mask;
        float ang = (float)pos[s] * inv_freq;
        const float conc = 0.1f * logf(32.0f) + 1.0f;
        cosv[j] = cosf(ang) * conc;
        sinv[j] = sinf(ang) * conc;
    }
    __syncthreads();
    const float qsc = 0.125f * 1.4426950408889634f;  // scale * log2(e)
    #pragma unroll
    for (int it = 0; it < 8; ++it) {
        int idx = it * 256 + tid;
        int h = idx >> 5, j = idx & 31;
        const ushort* src = qkv + (size_t)s * QKV_DIM + h * HD;
        float x1 = b2f(src[j]), x2 = b2f(src[j + 32]);
        float c = cosv[j], sn = sinv[j];
        ushort* dst = q_ro + ((size_t)h * SEQ + s) * HD;
        dst[j]      = f2b_bits((x1 * c - x2 * sn) * qsc);
        dst[j + 32] = f2b_bits((x2 * c + x1 * sn) * qsc);
    }
    {
        int h = tid >> 5, j = tid & 31;
        const ushort* src = qkv + (size_t)s * QKV_DIM + Q_SZ + h * HD;
        float x1 = b2f(src[j]), x2 = b2f(src[j + 32]);
        float c = cosv[j], sn = sinv[j];
        ushort* dst = k_ro + ((size_t)h * SEQ + s) * HD;
        dst[j]      = f2b_bits(x1 * c - x2 * sn);
        dst[j + 32] = f2b_bits(x2 * c + x1 * sn);
    }
}

// ---------------- V transpose: qkv[s][4608 + kh*64 + d] -> vT[kh][d][s] ----------------
__global__ __launch_bounds__(256) void vtrans_kernel(const ushort* __restrict__ qkv, ushort* __restrict__ vT) {
    __shared__ ushort t[64][65];
    const int kh = blockIdx.x >> 5;
    const int s0 = (blockIdx.x & 31) * 64;
    const int tid = threadIdx.x;
    #pragma unroll
    for (int it = 0; it < 16; ++it) {
        int e = it * 256 + tid;
        int sl = e >> 6, d = e & 63;
        t[d][sl] = qkv[(size_t)(s0 + sl) * QKV_DIM + Q_SZ + K_SZ + kh * HD + d];
    }
    __syncthreads();
    #pragma unroll
    for (int it = 0; it < 16; ++it) {
        int e = it * 256 + tid;
        int d = e >> 6, sl = e & 63;
        vT[((size_t)kh * HD + d) * SEQ + s0 + sl] = t[d][sl];
    }
}

// ---------------- attention v9: merged strips + V DIRECT FROM GLOBAL (L2-resident) ----------------
// m169 precedent: V-staging is pure overhead when V L2-fits (512KB K+V per kv-head,
// one kv-head per XCD via swizzle). V fragments are strip-invariant -> loaded once
// per tile into regs, issued BEFORE QK/softmax (~400cy) which hides L2 latency.
// LDS = Kb dbuf 16K + Pl 8K = 24KB. Staging per tile: 2 llds16/thread (K only).
__global__ __launch_bounds__(256, 4) void attn_kernel(
    const ushort* __restrict__ q_ro, const ushort* __restrict__ k_ro,
    const ushort* __restrict__ vT, const float* __restrict__ sinks,
    ushort* __restrict__ attn_out)
{
    __shared__ __align__(16) ushort Kb[2][4096];
    __shared__ __align__(16) ushort Pl[4][1024];

    const int tid = threadIdx.x;
    const int lane = tid & 63;
    const int w = tid >> 6;
    const int l15 = lane & 15;
    const int l4 = lane >> 4;

    // XCD-chunked bijective swizzle: 1024 blocks, XCD x owns wgid [x*128,(x+1)*128) = one kv-head
    int wg = blockIdx.x;
    int wgid = (wg & 7) * 128 + (wg >> 3);
    const int kh = wgid >> 7;        // 0..7
    const int qh = (wgid >> 4) & 7;  // 0..7
    const int pp = wgid & 15;        // 0..15
    const int h = kh * 8 + qh;

    const float snk = sinks[h];
    char* pbase = (char*)&Pl[w][0];

    const short oneb = (short)0x3F80;  // bf16 1.0
    const bf16x8 bones = {oneb, oneb, oneb, oneb, oneb, oneb, oneb, oneb};

    // ---- hoisted staging addresses (2 chunks/thread, K only) ----
    const int i0 = tid, i1 = 256 + tid;
    const int r0 = i0 >> 3, cs0 = (i0 ^ r0) & 7;
    const int r1 = i1 >> 3, cs1 = (i1 ^ r1) & 7;
    const ushort* gK0 = k_ro + (size_t)kh * (SEQ * 64) + r0 * 64 + cs0 * 8;
    const ushort* gK1 = k_ro + (size_t)kh * (SEQ * 64) + r1 * 64 + cs1 * 8;
    const int ld0 = (tid & ~63) * 8, ld1 = (256 + (tid & ~63)) * 8;

    // ---- per-lane V base: row (kh*64 + l15), col chunk l4*8 ----
    const ushort* gVbase = vT + ((size_t)kh * 64 + l15) * SEQ + l4 * 8;

    // ---- per-lane LDS byte bases ----
    const int swz = (l15 & 7) << 4;
    const int kvbase = l15 * 128 + ((l4 * 16) ^ swz);  // K/P frag reads (^ kc*64, + c*2048)
    const int pwbase = l15 * 128 + ((l4 * 8) ^ swz);   // P writes (^ c*32)

    auto stage = [&](int bs, int k0) {
        llds16(gK0 + k0 * 64, &Kb[bs][ld0]);
        llds16(gK1 + k0 * 64, &Kb[bs][ld1]);
    };

    const int qtA = pp;            // 0..15
    const int qtB = 31 - pp;       // 16..31
    const int qwA = qtA * 64 + w * 16;
    const int qwB = qtB * 64 + w * 16;
    const int ktA0 = (qtA >= 2) ? (qtA - 2) : 0;
    const int ktB0 = qtB - 2;      // >= 14

    bf16x8 aqA[2], aqB[2];
    #pragma unroll
    for (int kc = 0; kc < 2; ++kc) {
        aqA[kc] = *reinterpret_cast<const bf16x8*>(
            q_ro + ((size_t)h * SEQ + qwA + l15) * HD + kc * 32 + l4 * 8);
        aqB[kc] = *reinterpret_cast<const bf16x8*>(
            q_ro + ((size_t)h * SEQ + qwB + l15) * HD + kc * 32 + l4 * 8);
    }

    f32x4 oA[4] = {}, oB[4] = {};
    f32x4 laccA = {0.f, 0.f, 0.f, 0.f}, laccB = {0.f, 0.f, 0.f, 0.f};

    int cur = 0;
    stage(0, ktA0 * 64);
    __syncthreads();

    // per-strip tile body: QK^T (swapped) -> mask -> exp2+pack -> P-LDS -> PV (V in regs)
    auto strip_body = [&](const bf16x8 (&aq)[2], f32x4 (&o)[4], f32x4& lacc,
                          int qw, int k0, const char* kbp, const bf16x8 (&bv)[2][4]) {
        f32x4 s[4];
        const f32x4 z = {0.f, 0.f, 0.f, 0.f};
        __builtin_amdgcn_s_setprio(1);
        #pragma unroll
        for (int c = 0; c < 4; ++c) {
            bf16x8 bk0 = *reinterpret_cast<const bf16x8*>(kbp + c * 2048 + kvbase);
            s[c] = __builtin_amdgcn_mfma_f32_16x16x32_bf16(bk0, aq[0], z, 0, 0, 0);
            bf16x8 bk1 = *reinterpret_cast<const bf16x8*>(kbp + c * 2048 + (kvbase ^ 64));
            s[c] = __builtin_amdgcn_mfma_f32_16x16x32_bf16(bk1, aq[1], s[c], 0, 0, 0);
        }
        __builtin_amdgcn_s_setprio(0);

        if (k0 < qw - 113) {           // first tile of this strip only
            int thr = qw + l15 - 128 - k0;
            #pragma unroll
            for (int c = 0; c < 4; ++c)
                #pragma unroll
                for (int r = 0; r < 4; ++r)
                    if (c * 16 + l4 * 4 + r < thr) s[c][r] = -1e30f;
        }

        #pragma unroll
        for (int c = 0; c < 4; ++c) {
            float p0 = exp2f(s[c][0]), p1 = exp2f(s[c][1]);
            float p2 = exp2f(s[c][2]), p3 = exp2f(s[c][3]);
            unsigned int pk0, pk1;
            asm("v_cvt_pk_bf16_f32 %0, %1, %2" : "=v"(pk0) : "v"(p0), "v"(p1));
            asm("v_cvt_pk_bf16_f32 %0, %1, %2" : "=v"(pk1) : "v"(p2), "v"(p3));
            uint2 pv; pv.x = pk0; pv.y = pk1;
            *reinterpret_cast<uint2*>(pbase + (pwbase ^ (c * 32))) = pv;
        }

        __builtin_amdgcn_s_setprio(1);
        #pragma unroll
        for (int kc = 0; kc < 2; ++kc) {
            bf16x8 pa = *reinterpret_cast<const bf16x8*>(pbase + (kvbase ^ (kc * 64)));
            lacc = __builtin_amdgcn_mfma_f32_16x16x32_bf16(pa, bones, lacc, 0, 0, 0);
            #pragma unroll
            for (int df = 0; df < 4; ++df)
                o[df] = __builtin_amdgcn_mfma_f32_16x16x32_bf16(pa, bv[kc][df], o[df], 0, 0, 0);
        }
        __builtin_amdgcn_s_setprio(0);
    };

    for (int kt = ktA0; kt < SEQ / 64; ++kt) {
        const int k0 = kt * 64;
        if (kt + 1 < SEQ / 64) stage(cur ^ 1, k0 + 64);

        // ---- V fragments for this tile (strip-invariant), issued before QK/softmax ----
        bf16x8 bv[2][4];
        #pragma unroll
        for (int kc = 0; kc < 2; ++kc)
            #pragma unroll
            for (int df = 0; df < 4; ++df)
                bv[kc][df] = *reinterpret_cast<const bf16x8*>(
                    gVbase + (size_t)df * 16 * SEQ + k0 + kc * 32);

        const char* kbp = (const char*)Kb[cur];
        strip_body(aqA, oA, laccA, qwA, k0, kbp, bv);
        if (kt >= ktB0) strip_body(aqB, oB, laccB, qwB, k0, kbp, bv);

        __syncthreads();  // drains vmcnt(0): next K tile staged; all waves done with cur
        cur ^= 1;
    }

    // ---- epilogue: denom = sum(p) + exp(sink), both strips ----
    {
        const float es = exp2f(snk * 1.4426950408889634f);
        float invA[4], invB[4];
        #pragma unroll
        for (int r = 0; r < 4; ++r) {
            invA[r] = 1.0f / (laccA[r] + es);
            invB[r] = 1.0f / (laccB[r] + es);
        }
        #pragma unroll
        for (int df = 0; df < 4; ++df)
            #pragma unroll
            for (int r = 0; r < 4; ++r) {
                int col = df * 16 + l15;
                int rowA = qwA + l4 * 4 + r;
                attn_out[(size_t)rowA * Q_SZ + h * HD + col] = f2b_bits(oA[df][r] * invA[r]);
                int rowB = qwB + l4 * 4 + r;
                attn_out[(size_t)rowB * Q_SZ + h * HD + col] = f2b_bits(oB[df][r] * invB[r]);
            }
    }
}

extern "C" void kernel_launch(void* const* d_in, const int* in_sizes, int n_in,
                              void* d_out, int out_size, void* d_ws, size_t ws_size,
                              hipStream_t stream) {
    const float* hidden = (const float*)d_in[0];
    const float* qkv_w  = (const float*)d_in[1];
    const float* qkv_b  = (const float*)d_in[2];
    const float* o_w    = (const float*)d_in[3];
    const float* o_b    = (const float*)d_in[4];
    const float* sinks  = (const float*)d_in[5];
    const int*   pos    = (const int*)d_in[6];
    float* out = (float*)d_out;

    char* ws = (char*)d_ws;
    size_t off = 0;
    auto alloc = [&](size_t bytes) {
        char* p = ws + off;
        off += (bytes + 255) & ~(size_t)255;
        return p;
    };
    ushort* hs_bf   = (ushort*)alloc((size_t)SEQ * HIDDEN * 2);
    ushort* wqkv_bf = (ushort*)alloc((size_t)QKV_DIM * HIDDEN * 2);
    ushort* qkv_bf  = (ushort*)alloc((size_t)SEQ * QKV_DIM * 2);
    ushort* q_ro    = (ushort*)alloc((size_t)NQ * SEQ * HD * 2);
    ushort* k_ro    = (ushort*)alloc((size_t)NKV * SEQ * HD * 2);
    ushort* vT      = (ushort*)alloc((size_t)NKV * HD * SEQ * 2);
    ushort* attn_bf = (ushort*)alloc((size_t)SEQ * Q_SZ * 2);
    ushort* wo_bf   = (ushort*)alloc((size_t)OW_NPAD * OW_K * 2);

    convert_all<<<2048, 256, 0, stream>>>(hidden, qkv_w, o_w, hs_bf, wqkv_bf, wo_bf);

    gemm_bt<1><<<(QKV_DIM / 128) * (SEQ / 128), 256, 0, stream>>>(
        hs_bf, wqkv_bf, qkv_b, qkv_bf, SEQ, QKV_DIM, HIDDEN, QKV_DIM, QKV_DIM);

    rope_kernel<<<SEQ, 256, 0, stream>>>(qkv_bf, pos, q_ro, k_ro);
    vtrans_kernel<<<NKV * 32, 256, 0, stream>>>(qkv_bf, vT);

    attn_kernel<<<1024, 256, 0, stream>>>(q_ro, k_ro, vT, sinks, attn_bf);

    gemm_bt64<0><<<(OW_NPAD / 128) * (SEQ / 64), 256, 0, stream>>>(
        attn_bf, wo_bf, o_b, out, SEQ, OW_NPAD, OW_K, OW_N, OW_N);
}

// Round 15
// 254.073 us; speedup vs baseline: 1.2788x; 1.2788x over previous
//
#include <hip/hip_runtime.h>
#include <hip/hip_bf16.h>
#include <stdint.h>

typedef __attribute__((ext_vector_type(4))) float f32x4;
typedef __attribute__((ext_vector_type(8))) short bf16x8;

#define SEQ 2048
#define HIDDEN 2880
#define NQ 64
#define NKV 8
#define HD 64
#define QKV_DIM 5120
#define Q_SZ 4096
#define K_SZ 512
#define OW_N 2880
#define OW_NPAD 2944
#define OW_K 4096

__device__ __forceinline__ unsigned short f2b_bits(float f) {
    unsigned int x = __float_as_uint(f);
    unsigned int r = (x + 0x7fffu + ((x >> 16) & 1u)) >> 16;  // RNE
    return (unsigned short)r;
}
__device__ __forceinline__ float b2f(unsigned short u) {
    return __uint_as_float(((unsigned int)u) << 16);
}

__device__ __forceinline__ void llds16(const ushort* g, ushort* l) {
    __builtin_amdgcn_global_load_lds(
        (const __attribute__((address_space(1))) void*)g,
        (__attribute__((address_space(3))) void*)l, 16, 0, 0);
}

// ---------------- fused fp32 -> bf16 conversion (hidden + qkv_w + o_w padded) ----------------
__global__ void convert_all(const float* __restrict__ hidden, const float* __restrict__ qkv_w,
                            const float* __restrict__ o_w, ushort* __restrict__ hs_bf,
                            ushort* __restrict__ wqkv_bf, ushort* __restrict__ wo_bf) {
    const int N1 = SEQ * HIDDEN / 4;                 // 1,474,560
    const int N2 = N1 + QKV_DIM * HIDDEN / 4;        // 5,160,960
    const int N3 = N2 + OW_NPAD * OW_K / 4;          // 8,175,616
    int i = blockIdx.x * blockDim.x + threadIdx.x;
    int stride = gridDim.x * blockDim.x;
    for (; i < N3; i += stride) {
        const float* src;
        ushort* dst;
        int j;
        if (i < N1) {
            j = i; src = hidden; dst = hs_bf;
        } else if (i < N2) {
            j = i - N1; src = qkv_w; dst = wqkv_bf;
        } else {
            j = i - N2; src = o_w; dst = wo_bf;
            if ((j >> 10) >= OW_N) {  // padded rows (row = j*4/4096)
                reinterpret_cast<ushort4*>(dst)[j] = make_ushort4(0, 0, 0, 0);
                continue;
            }
        }
        float4 v = reinterpret_cast<const float4*>(src)[j];
        reinterpret_cast<ushort4*>(dst)[j] =
            make_ushort4(f2b_bits(v.x), f2b_bits(v.y), f2b_bits(v.z), f2b_bits(v.w));
    }
}

// ---------------- bf16 GEMM, B^T layout, 128x128 tile, BK=64, single-buffered (r6/r9 proven) ----------------
template<int OUT_BF16>
__global__ __launch_bounds__(256) void gemm_bt(
    const ushort* __restrict__ A, const ushort* __restrict__ B,
    const float* __restrict__ bias, void* __restrict__ Cout,
    int M, int N, int K, int Nreal, int ldC)
{
    __shared__ __align__(16) ushort As[128 * 64];
    __shared__ __align__(16) ushort Bs[128 * 64];
    const int tid = threadIdx.x;
    const int lane = tid & 63;
    const int w = tid >> 6;
    const int wr = w >> 1, wc = w & 1;

    const int nwg = gridDim.x;
    const int per = nwg >> 3;
    const int wgid = (blockIdx.x & 7) * per + (blockIdx.x >> 3);
    const int m0 = (wgid & 15) * 128;   // M-tile fastest (16 M-tiles)
    const int n0 = (wgid >> 4) * 128;   // N-tile chunk-contiguous per XCD

    f32x4 acc[4][4] = {};

    for (int k0 = 0; k0 < K; k0 += 64) {
        #pragma unroll
        for (int it = 0; it < 4; ++it) {
            int i = it * 256 + tid;
            int row = i >> 3;
            int col16 = (i ^ (row & 7)) & 7;
            llds16(A + (size_t)(m0 + row) * K + k0 + col16 * 8,
                   As + (size_t)(it * 256 + (tid & ~63)) * 8);
            llds16(B + (size_t)(n0 + row) * K + k0 + col16 * 8,
                   Bs + (size_t)(it * 256 + (tid & ~63)) * 8);
        }
        __syncthreads();
        #pragma unroll
        for (int kk = 0; kk < 2; ++kk) {
            bf16x8 a[4], b[4];
            #pragma unroll
            for (int mi = 0; mi < 4; ++mi) {
                int row = wr * 64 + mi * 16 + (lane & 15);
                int byte = row * 128 + kk * 64 + (lane >> 4) * 16;
                byte ^= (row & 7) << 4;
                a[mi] = *reinterpret_cast<const bf16x8*>(reinterpret_cast<const char*>(As) + byte);
            }
            #pragma unroll
            for (int ni = 0; ni < 4; ++ni) {
                int row = wc * 64 + ni * 16 + (lane & 15);
                int byte = row * 128 + kk * 64 + (lane >> 4) * 16;
                byte ^= (row & 7) << 4;
                b[ni] = *reinterpret_cast<const bf16x8*>(reinterpret_cast<const char*>(Bs) + byte);
            }
            #pragma unroll
            for (int mi = 0; mi < 4; ++mi)
                #pragma unroll
                for (int ni = 0; ni < 4; ++ni)
                    acc[mi][ni] = __builtin_amdgcn_mfma_f32_16x16x32_bf16(a[mi], b[ni], acc[mi][ni], 0, 0, 0);
        }
        __syncthreads();
    }

    #pragma unroll
    for (int mi = 0; mi < 4; ++mi) {
        int gr = m0 + wr * 64 + mi * 16 + (lane >> 4) * 4;
        #pragma unroll
        for (int ni = 0; ni < 4; ++ni) {
            int gc = n0 + wc * 64 + ni * 16 + (lane & 15);
            if (gc < Nreal) {
                float bv = bias[gc];
                #pragma unroll
                for (int r = 0; r < 4; ++r) {
                    float v = acc[mi][ni][r] + bv;
                    if (OUT_BF16)
                        ((ushort*)Cout)[(size_t)(gr + r) * ldC + gc] = f2b_bits(v);
                    else
                        ((float*)Cout)[(size_t)(gr + r) * ldC + gc] = v;
                }
            }
        }
    }
}

// ---------------- bf16 GEMM, 64x128 tile (O-proj; r9 proven) ----------------
template<int OUT_BF16>
__global__ __launch_bounds__(256) void gemm_bt64(
    const ushort* __restrict__ A, const ushort* __restrict__ B,
    const float* __restrict__ bias, void* __restrict__ Cout,
    int M, int N, int K, int Nreal, int ldC)
{
    __shared__ __align__(16) ushort As[64 * 64];
    __shared__ __align__(16) ushort Bs[128 * 64];
    const int tid = threadIdx.x;
    const int lane = tid & 63;
    const int w = tid >> 6;
    const int l15 = lane & 15;
    const int l4 = lane >> 4;

    const int nwg = gridDim.x;
    const int per = nwg >> 3;
    const int wgid = (blockIdx.x & 7) * per + (blockIdx.x >> 3);
    const int m0 = (wgid & 31) * 64;    // M-tile fastest (32 M-tiles)
    const int n0 = (wgid >> 5) * 128;   // N-tile chunk-contiguous per XCD

    f32x4 acc[4][2] = {};

    for (int k0 = 0; k0 < K; k0 += 64) {
        #pragma unroll
        for (int it = 0; it < 2; ++it) {
            int i = it * 256 + tid;
            int row = i >> 3;
            int col16 = (i ^ (row & 7)) & 7;
            llds16(A + (size_t)(m0 + row) * K + k0 + col16 * 8,
                   As + (size_t)(it * 256 + (tid & ~63)) * 8);
        }
        #pragma unroll
        for (int it = 0; it < 4; ++it) {
            int i = it * 256 + tid;
            int row = i >> 3;
            int col16 = (i ^ (row & 7)) & 7;
            llds16(B + (size_t)(n0 + row) * K + k0 + col16 * 8,
                   Bs + (size_t)(it * 256 + (tid & ~63)) * 8);
        }
        __syncthreads();
        #pragma unroll
        for (int kk = 0; kk < 2; ++kk) {
            bf16x8 a[4], b[2];
            #pragma unroll
            for (int mi = 0; mi < 4; ++mi) {
                int row = mi * 16 + l15;
                int byte = row * 128 + kk * 64 + l4 * 16;
                byte ^= (row & 7) << 4;
                a[mi] = *reinterpret_cast<const bf16x8*>(reinterpret_cast<const char*>(As) + byte);
            }
            #pragma unroll
            for (int ni = 0; ni < 2; ++ni) {
                int row = w * 32 + ni * 16 + l15;
                int byte = row * 128 + kk * 64 + l4 * 16;
                byte ^= (row & 7) << 4;
                b[ni] = *reinterpret_cast<const bf16x8*>(reinterpret_cast<const char*>(Bs) + byte);
            }
            #pragma unroll
            for (int mi = 0; mi < 4; ++mi)
                #pragma unroll
                for (int ni = 0; ni < 2; ++ni)
                    acc[mi][ni] = __builtin_amdgcn_mfma_f32_16x16x32_bf16(a[mi], b[ni], acc[mi][ni], 0, 0, 0);
        }
        __syncthreads();
    }

    #pragma unroll
    for (int mi = 0; mi < 4; ++mi) {
        int gr = m0 + mi * 16 + l4 * 4;
        #pragma unroll
        for (int ni = 0; ni < 2; ++ni) {
            int gc = n0 + w * 32 + ni * 16 + l15;
            if (gc < Nreal) {
                float bv = bias[gc];
                #pragma unroll
                for (int r = 0; r < 4; ++r) {
                    float v = acc[mi][ni][r] + bv;
                    if (OUT_BF16)
                        ((ushort*)Cout)[(size_t)(gr + r) * ldC + gc] = f2b_bits(v);
                    else
                        ((float*)Cout)[(size_t)(gr + r) * ldC + gc] = v;
                }
            }
        }
    }
}

// ---------------- RoPE (YaRN) + split + q-prescale ----------------
__global__ __launch_bounds__(256) void rope_kernel(
    const ushort* __restrict__ qkv, const int* __restrict__ pos,
    ushort* __restrict__ q_ro, ushort* __restrict__ k_ro)
{
    __shared__ float cosv[32], sinv[32];
    const int s = blockIdx.x;
    const int tid = threadIdx.x;
    if (tid < 32) {
        int j = tid;
        const float logbase = logf(150000.0f);
        float freq = expf((float)j * (logbase / 32.0f));  // BASE^(j/32)
        float interp = 1.0f / (32.0f * freq);
        float extrap = 1.0f / freq;
        const float twopi = 6.283185307179586f;
        float low  = 32.0f * logf(4096.0f / (32.0f * twopi)) / logbase;
        float high = 32.0f * logf(4096.0f / (1.0f  * twopi)) / logbase;
        float ramp = ((float)j - low) / (high - low);
        float mask = 1.0f - fminf(fmaxf(ramp, 0.0f), 1.0f);
        float inv_freq = interp * (1.0f - mask) + extrap * mask;
        float ang = (float)pos[s] * inv_freq;
        const float conc = 0.1f * logf(32.0f) + 1.0f;
        cosv[j] = cosf(ang) * conc;
        sinv[j] = sinf(ang) * conc;
    }
    __syncthreads();
    const float qsc = 0.125f * 1.4426950408889634f;  // scale * log2(e)
    #pragma unroll
    for (int it = 0; it < 8; ++it) {
        int idx = it * 256 + tid;
        int h = idx >> 5, j = idx & 31;
        const ushort* src = qkv + (size_t)s * QKV_DIM + h * HD;
        float x1 = b2f(src[j]), x2 = b2f(src[j + 32]);
        float c = cosv[j], sn = sinv[j];
        ushort* dst = q_ro + ((size_t)h * SEQ + s) * HD;
        dst[j]      = f2b_bits((x1 * c - x2 * sn) * qsc);
        dst[j + 32] = f2b_bits((x2 * c + x1 * sn) * qsc);
    }
    {
        int h = tid >> 5, j = tid & 31;
        const ushort* src = qkv + (size_t)s * QKV_DIM + Q_SZ + h * HD;
        float x1 = b2f(src[j]), x2 = b2f(src[j + 32]);
        float c = cosv[j], sn = sinv[j];
        ushort* dst = k_ro + ((size_t)h * SEQ + s) * HD;
        dst[j]      = f2b_bits(x1 * c - x2 * sn);
        dst[j + 32] = f2b_bits(x2 * c + x1 * sn);
    }
}

// ---------------- V transpose: qkv[s][4608 + kh*64 + d] -> vT[kh][d][s] ----------------
__global__ __launch_bounds__(256) void vtrans_kernel(const ushort* __restrict__ qkv, ushort* __restrict__ vT) {
    __shared__ ushort t[64][65];
    const int kh = blockIdx.x >> 5;
    const int s0 = (blockIdx.x & 31) * 64;
    const int tid = threadIdx.x;
    #pragma unroll
    for (int it = 0; it < 16; ++it) {
        int e = it * 256 + tid;
        int sl = e >> 6, d = e & 63;
        t[d][sl] = qkv[(size_t)(s0 + sl) * QKV_DIM + Q_SZ + K_SZ + kh * HD + d];
    }
    __syncthreads();
    #pragma unroll
    for (int it = 0; it < 16; ++it) {
        int e = it * 256 + tid;
        int d = e >> 6, sl = e & 63;
        vT[((size_t)kh * HD + d) * SEQ + s0 + sl] = t[d][sl];
    }
}

// ---------------- attention v8 (r13 proven): MERGED paired strips, one k-loop ----------------
// Block owns strips A=p and B=31-p. B's tile range [29-p,32) is a subset of A's
// [max(0,p-2),32), so each K/V tile is staged ONCE; strip B computed only when
// kt >= 29-p. v5 pipeline otherwise (Pl buffer, dbuf K+V via global_load_lds
// coalesced 1KB transactions — r14 lesson: direct per-lane V reads break coalescing).
__global__ __launch_bounds__(256, 4) void attn_kernel(
    const ushort* __restrict__ q_ro, const ushort* __restrict__ k_ro,
    const ushort* __restrict__ vT, const float* __restrict__ sinks,
    ushort* __restrict__ attn_out)
{
    __shared__ __align__(16) ushort Kb[2][4096];
    __shared__ __align__(16) ushort Vb[2][4096];
    __shared__ __align__(16) ushort Pl[4][1024];

    const int tid = threadIdx.x;
    const int lane = tid & 63;
    const int w = tid >> 6;
    const int l15 = lane & 15;
    const int l4 = lane >> 4;

    // XCD-chunked bijective swizzle: 1024 blocks, XCD x owns wgid [x*128,(x+1)*128) = one kv-head
    int wg = blockIdx.x;
    int wgid = (wg & 7) * 128 + (wg >> 3);
    const int kh = wgid >> 7;        // 0..7
    const int qh = (wgid >> 4) & 7;  // 0..7
    const int pp = wgid & 15;        // 0..15
    const int h = kh * 8 + qh;

    const float snk = sinks[h];
    char* pbase = (char*)&Pl[w][0];

    const short oneb = (short)0x3F80;  // bf16 1.0
    const bf16x8 bones = {oneb, oneb, oneb, oneb, oneb, oneb, oneb, oneb};

    // ---- hoisted staging addresses (2 chunks/thread/array) ----
    const int i0 = tid, i1 = 256 + tid;
    const int r0 = i0 >> 3, cs0 = (i0 ^ r0) & 7;
    const int r1 = i1 >> 3, cs1 = (i1 ^ r1) & 7;
    const ushort* gK0 = k_ro + (size_t)kh * (SEQ * 64) + r0 * 64 + cs0 * 8;
    const ushort* gK1 = k_ro + (size_t)kh * (SEQ * 64) + r1 * 64 + cs1 * 8;
    const ushort* gV0 = vT + ((size_t)kh * 64 + r0) * SEQ + cs0 * 8;
    const ushort* gV1 = vT + ((size_t)kh * 64 + r1) * SEQ + cs1 * 8;
    const int ld0 = (tid & ~63) * 8, ld1 = (256 + (tid & ~63)) * 8;

    // ---- per-lane LDS byte bases ----
    const int swz = (l15 & 7) << 4;
    const int kvbase = l15 * 128 + ((l4 * 16) ^ swz);  // K/V frag reads (^ kc*64, + c/df*2048)
    const int pwbase = l15 * 128 + ((l4 * 8) ^ swz);   // P writes (^ c*32)

    auto stage = [&](int bs, int k0) {
        llds16(gK0 + k0 * 64, &Kb[bs][ld0]);
        llds16(gK1 + k0 * 64, &Kb[bs][ld1]);
        llds16(gV0 + k0,      &Vb[bs][ld0]);
        llds16(gV1 + k0,      &Vb[bs][ld1]);
    };

    const int qtA = pp;            // 0..15
    const int qtB = 31 - pp;       // 16..31
    const int qwA = qtA * 64 + w * 16;
    const int qwB = qtB * 64 + w * 16;
    const int ktA0 = (qtA >= 2) ? (qtA - 2) : 0;
    const int ktB0 = qtB - 2;      // >= 14

    bf16x8 aqA[2], aqB[2];
    #pragma unroll
    for (int kc = 0; kc < 2; ++kc) {
        aqA[kc] = *reinterpret_cast<const bf16x8*>(
            q_ro + ((size_t)h * SEQ + qwA + l15) * HD + kc * 32 + l4 * 8);
        aqB[kc] = *reinterpret_cast<const bf16x8*>(
            q_ro + ((size_t)h * SEQ + qwB + l15) * HD + kc * 32 + l4 * 8);
    }

    f32x4 oA[4] = {}, oB[4] = {};
    f32x4 laccA = {0.f, 0.f, 0.f, 0.f}, laccB = {0.f, 0.f, 0.f, 0.f};

    int cur = 0;
    stage(0, ktA0 * 64);
    __syncthreads();

    // per-strip tile body: QK^T (swapped) -> mask -> exp2+pack -> P-LDS -> PV
    auto strip_body = [&](const bf16x8 (&aq)[2], f32x4 (&o)[4], f32x4& lacc,
                          int qw, int k0, const char* kbp, const char* vbp) {
        f32x4 s[4];
        const f32x4 z = {0.f, 0.f, 0.f, 0.f};
        __builtin_amdgcn_s_setprio(1);
        #pragma unroll
        for (int c = 0; c < 4; ++c) {
            bf16x8 bk0 = *reinterpret_cast<const bf16x8*>(kbp + c * 2048 + kvbase);
            s[c] = __builtin_amdgcn_mfma_f32_16x16x32_bf16(bk0, aq[0], z, 0, 0, 0);
            bf16x8 bk1 = *reinterpret_cast<const bf16x8*>(kbp + c * 2048 + (kvbase ^ 64));
            s[c] = __builtin_amdgcn_mfma_f32_16x16x32_bf16(bk1, aq[1], s[c], 0, 0, 0);
        }
        __builtin_amdgcn_s_setprio(0);

        if (k0 < qw - 113) {           // first tile of this strip only
            int thr = qw + l15 - 128 - k0;
            #pragma unroll
            for (int c = 0; c < 4; ++c)
                #pragma unroll
                for (int r = 0; r < 4; ++r)
                    if (c * 16 + l4 * 4 + r < thr) s[c][r] = -1e30f;
        }

        #pragma unroll
        for (int c = 0; c < 4; ++c) {
            float p0 = exp2f(s[c][0]), p1 = exp2f(s[c][1]);
            float p2 = exp2f(s[c][2]), p3 = exp2f(s[c][3]);
            unsigned int pk0, pk1;
            asm("v_cvt_pk_bf16_f32 %0, %1, %2" : "=v"(pk0) : "v"(p0), "v"(p1));
            asm("v_cvt_pk_bf16_f32 %0, %1, %2" : "=v"(pk1) : "v"(p2), "v"(p3));
            uint2 pv; pv.x = pk0; pv.y = pk1;
            *reinterpret_cast<uint2*>(pbase + (pwbase ^ (c * 32))) = pv;
        }

        __builtin_amdgcn_s_setprio(1);
        #pragma unroll
        for (int kc = 0; kc < 2; ++kc) {
            bf16x8 pa = *reinterpret_cast<const bf16x8*>(pbase + (kvbase ^ (kc * 64)));
            lacc = __builtin_amdgcn_mfma_f32_16x16x32_bf16(pa, bones, lacc, 0, 0, 0);
            #pragma unroll
            for (int df = 0; df < 4; ++df) {
                bf16x8 bv = *reinterpret_cast<const bf16x8*>(vbp + df * 2048 + (kvbase ^ (kc * 64)));
                o[df] = __builtin_amdgcn_mfma_f32_16x16x32_bf16(pa, bv, o[df], 0, 0, 0);
            }
        }
        __builtin_amdgcn_s_setprio(0);
    };

    for (int kt = ktA0; kt < SEQ / 64; ++kt) {
        const int k0 = kt * 64;
        if (kt + 1 < SEQ / 64) stage(cur ^ 1, k0 + 64);

        const char* kbp = (const char*)Kb[cur];
        const char* vbp = (const char*)Vb[cur];
        strip_body(aqA, oA, laccA, qwA, k0, kbp, vbp);
        if (kt >= ktB0) strip_body(aqB, oB, laccB, qwB, k0, kbp, vbp);

        __syncthreads();  // drains vmcnt(0): next tile staged; all waves done with cur
        cur ^= 1;
    }

    // ---- epilogue: denom = sum(p) + exp(sink), both strips ----
    {
        const float es = exp2f(snk * 1.4426950408889634f);
        float invA[4], invB[4];
        #pragma unroll
        for (int r = 0; r < 4; ++r) {
            invA[r] = 1.0f / (laccA[r] + es);
            invB[r] = 1.0f / (laccB[r] + es);
        }
        #pragma unroll
        for (int df = 0; df < 4; ++df)
            #pragma unroll
            for (int r = 0; r < 4; ++r) {
                int col = df * 16 + l15;
                int rowA = qwA + l4 * 4 + r;
                attn_out[(size_t)rowA * Q_SZ + h * HD + col] = f2b_bits(oA[df][r] * invA[r]);
                int rowB = qwB + l4 * 4 + r;
                attn_out[(size_t)rowB * Q_SZ + h * HD + col] = f2b_bits(oB[df][r] * invB[r]);
            }
    }
}

extern "C" void kernel_launch(void* const* d_in, const int* in_sizes, int n_in,
                              void* d_out, int out_size, void* d_ws, size_t ws_size,
                              hipStream_t stream) {
    const float* hidden = (const float*)d_in[0];
    const float* qkv_w  = (const float*)d_in[1];
    const float* qkv_b  = (const float*)d_in[2];
    const float* o_w    = (const float*)d_in[3];
    const float* o_b    = (const float*)d_in[4];
    const float* sinks  = (const float*)d_in[5];
    const int*   pos    = (const int*)d_in[6];
    float* out = (float*)d_out;

    char* ws = (char*)d_ws;
    size_t off = 0;
    auto alloc = [&](size_t bytes) {
        char* p = ws + off;
        off += (bytes + 255) & ~(size_t)255;
        return p;
    };
    ushort* hs_bf   = (ushort*)alloc((size_t)SEQ * HIDDEN * 2);
    ushort* wqkv_bf = (ushort*)alloc((size_t)QKV_DIM * HIDDEN * 2);
    ushort* qkv_bf  = (ushort*)alloc((size_t)SEQ * QKV_DIM * 2);
    ushort* q_ro    = (ushort*)alloc((size_t)NQ * SEQ * HD * 2);
    ushort* k_ro    = (ushort*)alloc((size_t)NKV * SEQ * HD * 2);
    ushort* vT      = (ushort*)alloc((size_t)NKV * HD * SEQ * 2);
    ushort* attn_bf = (ushort*)alloc((size_t)SEQ * Q_SZ * 2);
    ushort* wo_bf   = (ushort*)alloc((size_t)OW_NPAD * OW_K * 2);

    convert_all<<<2048, 256, 0, stream>>>(hidden, qkv_w, o_w, hs_bf, wqkv_bf, wo_bf);

    gemm_bt<1><<<(QKV_DIM / 128) * (SEQ / 128), 256, 0, stream>>>(
        hs_bf, wqkv_bf, qkv_b, qkv_bf, SEQ, QKV_DIM, HIDDEN, QKV_DIM, QKV_DIM);

    rope_kernel<<<SEQ, 256, 0, stream>>>(qkv_bf, pos, q_ro, k_ro);
    vtrans_kernel<<<NKV * 32, 256, 0, stream>>>(qkv_bf, vT);

    attn_kernel<<<1024, 256, 0, stream>>>(q_ro, k_ro, vT, sinks, attn_bf);

    gemm_bt64<0><<<(OW_NPAD / 128) * (SEQ / 64), 256, 0, stream>>>(
        attn_bf, wo_bf, o_b, out, SEQ, OW_NPAD, OW_K, OW_N, OW_N);
}